// Round 1
// baseline (8052.966 us; speedup 1.0000x reference)
//
#include <hip/hip_runtime.h>
#include <hip/hip_bf16.h>

typedef __hip_bfloat16 bf16;
typedef __attribute__((ext_vector_type(8))) short bf16x8;
typedef __attribute__((ext_vector_type(4))) float f32x4;

#define B_SZ 64
#define D_MODEL 768
#define NTOK 197
#define MTOK (B_SZ * NTOK)      // 12608
#define NHEAD 12
#define HDIM 64
#define MLP_DIM 3072
#define NCLS 1000

// ---------------------------------------------------------------------------
// fp32 -> bf16 conversion (generic)
__global__ __launch_bounds__(256) void cvt_kernel(const float* __restrict__ in,
                                                  bf16* __restrict__ out, int n) {
    int i = ((int)blockIdx.x * 256 + (int)threadIdx.x) * 4;
    if (i >= n) return;
    float4 v = *(const float4*)(in + i);
    __align__(8) bf16 t[4] = {__float2bfloat16(v.x), __float2bfloat16(v.y),
                              __float2bfloat16(v.z), __float2bfloat16(v.w)};
    *(uint2*)(out + i) = *(uint2*)t;
}

// per-layer weight pack: qkv_w | proj_w | fc1_w | fc2_w  -> one bf16 buffer
#define R_QKV 1769472   // 2304*768
#define R_PRJ 589824    // 768*768
#define R_FC  2359296   // 3072*768
#define R_TOT 7077888
__global__ __launch_bounds__(256) void cvt_layer_kernel(
    const float* __restrict__ qw, const float* __restrict__ pw,
    const float* __restrict__ f1, const float* __restrict__ f2,
    bf16* __restrict__ out) {
    size_t i = ((size_t)blockIdx.x * 256 + threadIdx.x) * 4;   // < R_TOT
    const float* src;
    if (i < R_QKV)                src = qw + i;
    else if (i < R_QKV + R_PRJ)   src = pw + (i - R_QKV);
    else if (i < R_QKV + R_PRJ + R_FC) src = f1 + (i - R_QKV - R_PRJ);
    else                          src = f2 + (i - R_QKV - R_PRJ - R_FC);
    float4 v = *(const float4*)src;
    __align__(8) bf16 t[4] = {__float2bfloat16(v.x), __float2bfloat16(v.y),
                              __float2bfloat16(v.z), __float2bfloat16(v.w)};
    *(uint2*)(out + i) = *(uint2*)t;
}

// ---------------------------------------------------------------------------
// im2row for the patch-embed GEMM: x[B,3,224,224] -> A[12544][768] bf16
__global__ __launch_bounds__(256) void im2row_kernel(const float* __restrict__ x,
                                                     bf16* __restrict__ out) {
    size_t idx = (size_t)blockIdx.x * 256 + threadIdx.x;  // 12544*768 total
    int c = (int)(idx % 768);
    int r = (int)(idx / 768);
    int b = r / 196, pp = r % 196;
    int ph = pp / 14, pw = pp % 14;
    int ch = c >> 8, rem = c & 255;
    int i = rem >> 4, j = rem & 15;
    float v = x[(((size_t)b * 3 + ch) * 224 + ph * 16 + i) * 224 + pw * 16 + j];
    out[idx] = __float2bfloat16(v);
}

// assemble h[B,197,768] = concat(cls, patches) + pos
__global__ __launch_bounds__(256) void assemble_kernel(
    const float* __restrict__ pe, const float* __restrict__ cls,
    const float* __restrict__ pos, float* __restrict__ h) {
    size_t idx = (size_t)blockIdx.x * 256 + threadIdx.x;  // 64*197*768 total
    int d = (int)(idx % 768);
    size_t t_ = idx / 768;
    int t = (int)(t_ % 197);
    size_t b = t_ / 197;
    float v = (t == 0) ? cls[d] : pe[((size_t)b * 196 + (t - 1)) * 768 + d];
    h[idx] = v + pos[(size_t)t * 768 + d];
}

// ---------------------------------------------------------------------------
// LayerNorm over 768, one block per row. out is bf16 (GEMM A operand).
__global__ __launch_bounds__(256) void ln_kernel(
    const float* __restrict__ in, int row_stride,
    const float* __restrict__ sc, const float* __restrict__ bi,
    bf16* __restrict__ out) {
    const int row = blockIdx.x;
    const float* xr = in + (size_t)row * row_stride;
    const int tid = threadIdx.x;
    float v0 = xr[tid], v1 = xr[tid + 256], v2 = xr[tid + 512];
    float s = v0 + v1 + v2;
    float q = v0 * v0 + v1 * v1 + v2 * v2;
#pragma unroll
    for (int off = 32; off > 0; off >>= 1) {
        s += __shfl_down(s, off);
        q += __shfl_down(q, off);
    }
    __shared__ float sw[4], qw_[4];
    __shared__ float stat[2];
    int wv = tid >> 6;
    if ((tid & 63) == 0) { sw[wv] = s; qw_[wv] = q; }
    __syncthreads();
    if (tid == 0) {
        float S = sw[0] + sw[1] + sw[2] + sw[3];
        float Q = qw_[0] + qw_[1] + qw_[2] + qw_[3];
        float mean = S * (1.f / 768.f);
        float var = Q * (1.f / 768.f) - mean * mean;
        stat[0] = mean;
        stat[1] = rsqrtf(var + 1e-5f);
    }
    __syncthreads();
    float mean = stat[0], rstd = stat[1];
    size_t o0 = (size_t)row * 768;
    out[o0 + tid]       = __float2bfloat16((v0 - mean) * rstd * sc[tid]       + bi[tid]);
    out[o0 + tid + 256] = __float2bfloat16((v1 - mean) * rstd * sc[tid + 256] + bi[tid + 256]);
    out[o0 + tid + 512] = __float2bfloat16((v2 - mean) * rstd * sc[tid + 512] + bi[tid + 512]);
}

// ---------------------------------------------------------------------------
// Generic bf16 MFMA GEMM:  C[M,Nt] = A[M,K] * W[Nt,K]^T + bias, optional
// exact-erf GELU, optional fp32 residual accumulate into Cout.
// 128x128 tile, BK=64, 256 threads (2x2 waves, each 64x64 via 4x4 mfma tiles).
// LDS rows are 64 elems (128B); 16B chunks XOR-swizzled by row&7 so frag
// ds_read_b128 is 2-way (free) instead of 8-way conflicted.
template <bool OUT_F32, bool RESID, bool GELU>
__global__ __launch_bounds__(256) void gemm_kernel(
    const bf16* __restrict__ A, const bf16* __restrict__ W,
    const float* __restrict__ bias, void* __restrict__ Cout,
    int M, int Nt, int K) {
    __shared__ __align__(16) bf16 As[128 * 64];
    __shared__ __align__(16) bf16 Bs[128 * 64];
    const int tid = threadIdx.x;
    const int lane = tid & 63;
    const int wave = tid >> 6;
    const int wm = wave >> 1, wn = wave & 1;
    const int m0 = blockIdx.y * 128, n0 = blockIdx.x * 128;
    const int m16 = lane & 15, kg = lane >> 4;

    f32x4 acc[4][4] = {};

    const int srow = tid >> 1;        // 0..127
    const int shalf = tid & 1;        // which 32-elem half of the 64-k row
    const bool va = (m0 + srow) < M;
    const bool vb = (n0 + srow) < Nt;
    const size_t a_base = (size_t)(m0 + srow) * K + shalf * 32;
    const size_t b_base = (size_t)(n0 + srow) * K + shalf * 32;
    const int r7 = srow & 7;
    const int cb = shalf * 4;
    const int sdst = srow * 64;

    for (int k0 = 0; k0 < K; k0 += 64) {
        __syncthreads();
        int4 z = make_int4(0, 0, 0, 0);
        const int4* ap = (const int4*)(A + a_base + k0);
        const int4* bp = (const int4*)(W + b_base + k0);
        int4 a0 = va ? ap[0] : z, a1 = va ? ap[1] : z;
        int4 a2 = va ? ap[2] : z, a3 = va ? ap[3] : z;
        int4 b0 = vb ? bp[0] : z, b1 = vb ? bp[1] : z;
        int4 b2 = vb ? bp[2] : z, b3 = vb ? bp[3] : z;
        *(int4*)&As[sdst + (((cb + 0) ^ r7) << 3)] = a0;
        *(int4*)&As[sdst + (((cb + 1) ^ r7) << 3)] = a1;
        *(int4*)&As[sdst + (((cb + 2) ^ r7) << 3)] = a2;
        *(int4*)&As[sdst + (((cb + 3) ^ r7) << 3)] = a3;
        *(int4*)&Bs[sdst + (((cb + 0) ^ r7) << 3)] = b0;
        *(int4*)&Bs[sdst + (((cb + 1) ^ r7) << 3)] = b1;
        *(int4*)&Bs[sdst + (((cb + 2) ^ r7) << 3)] = b2;
        *(int4*)&Bs[sdst + (((cb + 3) ^ r7) << 3)] = b3;
        __syncthreads();
#pragma unroll
        for (int ks = 0; ks < 2; ++ks) {
            bf16x8 af[4], bfv[4];
            const int ch = ((ks << 2) + kg) ^ (m16 & 7);
#pragma unroll
            for (int t = 0; t < 4; ++t)
                af[t] = *(const bf16x8*)&As[(wm * 64 + t * 16 + m16) * 64 + (ch << 3)];
#pragma unroll
            for (int t = 0; t < 4; ++t)
                bfv[t] = *(const bf16x8*)&Bs[(wn * 64 + t * 16 + m16) * 64 + (ch << 3)];
#pragma unroll
            for (int i = 0; i < 4; ++i)
#pragma unroll
                for (int j = 0; j < 4; ++j)
                    acc[i][j] = __builtin_amdgcn_mfma_f32_16x16x32_bf16(
                        af[i], bfv[j], acc[i][j], 0, 0, 0);
        }
    }
    // epilogue: C/D layout col=lane&15, row=quad*4+reg  [m89-verified]
    const int quad = lane >> 4;
#pragma unroll
    for (int i = 0; i < 4; ++i) {
        const int rbase = m0 + wm * 64 + i * 16 + quad * 4;
#pragma unroll
        for (int j = 0; j < 4; ++j) {
            const int col = n0 + wn * 64 + j * 16 + m16;
            if (col >= Nt) continue;
            const float bv = bias[col];
#pragma unroll
            for (int r = 0; r < 4; ++r) {
                const int row = rbase + r;
                if (row >= M) continue;
                float v = acc[i][j][r] + bv;
                if (GELU) v = 0.5f * v * (1.f + erff(v * 0.7071067811865476f));
                if (OUT_F32) {
                    float* op = (float*)Cout + (size_t)row * Nt + col;
                    if (RESID) *op += v; else *op = v;
                } else {
                    ((bf16*)Cout)[(size_t)row * Nt + col] = __float2bfloat16(v);
                }
            }
        }
    }
}

// ---------------------------------------------------------------------------
// Fused attention. One block per (b, head). K,V staged in LDS once; loop over
// 7 Q-tiles of 32 rows: S = Q K^T (mfma) -> LDS fp32 -> softmax -> P bf16 in
// A-operand layout -> O = P V (mfma) -> store o[b,i, h*64+d].
__global__ __launch_bounds__(256) void attn_kernel(const bf16* __restrict__ qkv,
                                                   bf16* __restrict__ o) {
    __shared__ __align__(16) bf16 Ks[208 * 72];   // K rows (j), stride 72 (conflict-free)
    __shared__ __align__(16) bf16 Vt[64 * 232];   // V^T: row=d, col=j, stride 232
    __shared__ __align__(16) bf16 Qs[32 * 72];
    __shared__ float Ss[32 * 209];
    __shared__ __align__(16) bf16 Ps[32 * 232];

    const int tid = threadIdx.x, lane = tid & 63, wave = tid >> 6;
    const int b = blockIdx.x / NHEAD, hh = blockIdx.x % NHEAD;
    const size_t base = (size_t)b * NTOK * 2304 + hh * 64;
    const int m16 = lane & 15, kg = lane >> 4, quad = lane >> 4;

    {  // stage K and V (transposed), zero-pad j in [197,224)
        const int jr = tid >> 3, ds = tid & 7;
        for (int j0 = 0; j0 < 224; j0 += 32) {
            int j = j0 + jr;
            if (j < 197) {
                int4 kv = *(const int4*)(qkv + base + 768 + (size_t)j * 2304 + ds * 8);
                *(int4*)&Ks[j * 72 + ds * 8] = kv;
                __align__(16) bf16 tmp[8];
                *(int4*)tmp = *(const int4*)(qkv + base + 1536 + (size_t)j * 2304 + ds * 8);
#pragma unroll
                for (int u = 0; u < 8; ++u) Vt[(ds * 8 + u) * 232 + j] = tmp[u];
            } else {
                if (j < 208) {
                    int4 z = make_int4(0, 0, 0, 0);
                    *(int4*)&Ks[j * 72 + ds * 8] = z;
                }
                bf16 zb = __float2bfloat16(0.f);
#pragma unroll
                for (int u = 0; u < 8; ++u) Vt[(ds * 8 + u) * 232 + j] = zb;
            }
        }
    }
    __syncthreads();

    for (int qt = 0; qt < 7; ++qt) {
        {  // stage 32 Q rows (zeros past token 196)
            const int r = tid >> 3, ds = tid & 7;
            int qi = qt * 32 + r;
            int4 v = make_int4(0, 0, 0, 0);
            if (qi < 197) v = *(const int4*)(qkv + base + (size_t)qi * 2304 + ds * 8);
            *(int4*)&Qs[r * 72 + ds * 8] = v;
        }
        __syncthreads();
        // S = Q K^T * scale ; wave w covers n-tiles w, w+4, ...
        bf16x8 qf[2][2];
#pragma unroll
        for (int mt = 0; mt < 2; ++mt)
#pragma unroll
            for (int ks = 0; ks < 2; ++ks)
                qf[mt][ks] = *(const bf16x8*)&Qs[(mt * 16 + m16) * 72 + ks * 32 + kg * 8];
        for (int nt = wave; nt < 13; nt += 4) {
            f32x4 s0 = {0.f, 0.f, 0.f, 0.f}, s1 = {0.f, 0.f, 0.f, 0.f};
#pragma unroll
            for (int ks = 0; ks < 2; ++ks) {
                bf16x8 kf = *(const bf16x8*)&Ks[(nt * 16 + m16) * 72 + ks * 32 + kg * 8];
                s0 = __builtin_amdgcn_mfma_f32_16x16x32_bf16(qf[0][ks], kf, s0, 0, 0, 0);
                s1 = __builtin_amdgcn_mfma_f32_16x16x32_bf16(qf[1][ks], kf, s1, 0, 0, 0);
            }
            const int col = nt * 16 + m16;
#pragma unroll
            for (int r = 0; r < 4; ++r) {
                Ss[(quad * 4 + r) * 209 + col]        = s0[r] * 0.125f;
                Ss[(16 + quad * 4 + r) * 209 + col]   = s1[r] * 0.125f;
            }
        }
        __syncthreads();
        {  // softmax: 8 threads per row
            const int r = tid >> 3, c0 = tid & 7;
            const float* srow = &Ss[r * 209];
            float mx = -3.0e38f;
            for (int c = c0; c < 197; c += 8) mx = fmaxf(mx, srow[c]);
#pragma unroll
            for (int off = 4; off > 0; off >>= 1) mx = fmaxf(mx, __shfl_xor(mx, off, 8));
            float l = 0.f;
            for (int c = c0; c < 197; c += 8) l += __expf(srow[c] - mx);
#pragma unroll
            for (int off = 4; off > 0; off >>= 1) l += __shfl_xor(l, off, 8);
            const float inv = 1.f / l;
            bf16* prow = &Ps[r * 232];
            for (int c = c0; c < 224; c += 8)
                prow[c] = __float2bfloat16(c < 197 ? __expf(srow[c] - mx) * inv : 0.f);
        }
        __syncthreads();
        // O = P V ; wave w owns d-tile w (16 d's)
        f32x4 o0 = {0.f, 0.f, 0.f, 0.f}, o1 = {0.f, 0.f, 0.f, 0.f};
#pragma unroll
        for (int ks = 0; ks < 7; ++ks) {
            bf16x8 vf = *(const bf16x8*)&Vt[(wave * 16 + m16) * 232 + ks * 32 + kg * 8];
            bf16x8 p0 = *(const bf16x8*)&Ps[m16 * 232 + ks * 32 + kg * 8];
            bf16x8 p1 = *(const bf16x8*)&Ps[(16 + m16) * 232 + ks * 32 + kg * 8];
            o0 = __builtin_amdgcn_mfma_f32_16x16x32_bf16(p0, vf, o0, 0, 0, 0);
            o1 = __builtin_amdgcn_mfma_f32_16x16x32_bf16(p1, vf, o1, 0, 0, 0);
        }
        const int dcol = hh * 64 + wave * 16 + m16;
#pragma unroll
        for (int r = 0; r < 4; ++r) {
            int q0i = qt * 32 + quad * 4 + r;
            if (q0i < 197) o[((size_t)b * NTOK + q0i) * 768 + dcol] = __float2bfloat16(o0[r]);
            int q1i = qt * 32 + 16 + quad * 4 + r;
            if (q1i < 197) o[((size_t)b * NTOK + q1i) * 768 + dcol] = __float2bfloat16(o1[r]);
        }
        // no trailing barrier needed: next iter's post-stage barrier orders
        // Qs/Ps reuse (Qs readers done before S-barrier, Ps writers gated).
    }
}

// ---------------------------------------------------------------------------
extern "C" void kernel_launch(void* const* d_in, const int* in_sizes, int n_in,
                              void* d_out, int out_size, void* d_ws, size_t ws_size,
                              hipStream_t stream) {
    const float* x      = (const float*)d_in[0];
    const float* conv_w = (const float*)d_in[1];
    const float* conv_b = (const float*)d_in[2];
    const float* cls_t  = (const float*)d_in[3];
    const float* pos    = (const float*)d_in[4];
    const float* qkv_w  = (const float*)d_in[5];
    const float* qkv_b  = (const float*)d_in[6];
    const float* proj_w = (const float*)d_in[7];
    const float* proj_b = (const float*)d_in[8];
    const float* n1_s   = (const float*)d_in[9];
    const float* n1_b   = (const float*)d_in[10];
    const float* n2_s   = (const float*)d_in[11];
    const float* n2_b   = (const float*)d_in[12];
    const float* fc1_w  = (const float*)d_in[13];
    const float* fc1_b  = (const float*)d_in[14];
    const float* fc2_w  = (const float*)d_in[15];
    const float* fc2_b  = (const float*)d_in[16];
    const float* enc_s  = (const float*)d_in[17];
    const float* enc_b  = (const float*)d_in[18];
    const float* head_w = (const float*)d_in[19];
    const float* head_b = (const float*)d_in[20];

    char* p = (char*)d_ws;
    auto take = [&](size_t bytes) -> char* {
        char* r = p;
        p += (bytes + 255) & ~(size_t)255;
        return r;
    };
    bf16* wb_layer = (bf16*)take((size_t)R_TOT * 2);            // 14.2 MB, reused per layer
    bf16* wb_conv  = (bf16*)take((size_t)589824 * 2);
    bf16* wb_head  = (bf16*)take((size_t)NCLS * 768 * 2);
    float* h       = (float*)take((size_t)MTOK * 768 * 4);      // residual stream, fp32
    bf16* y        = (bf16*)take((size_t)MTOK * 768 * 2);       // LN output
    char* qkv_raw  = take((size_t)MTOK * 2304 * 2);
    bf16* qkvb     = (bf16*)qkv_raw;
    float* pe_out  = (float*)qkv_raw;                           // alias (used pre-loop only)
    bf16* o        = (bf16*)take((size_t)MTOK * 768 * 2);
    char* mid_raw  = take((size_t)MTOK * 3072 * 2);
    bf16* mid      = (bf16*)mid_raw;
    bf16* peA      = (bf16*)mid_raw;                            // alias (used pre-loop only)
    bf16* yh       = (bf16*)take((size_t)64 * 768 * 2);

    // ---- patch embed ----
    cvt_kernel<<<576, 256, 0, stream>>>(conv_w, wb_conv, 589824);
    cvt_kernel<<<750, 256, 0, stream>>>(head_w, wb_head, NCLS * 768);
    im2row_kernel<<<37632, 256, 0, stream>>>(x, peA);
    gemm_kernel<true, false, false><<<dim3(6, 98), 256, 0, stream>>>(
        peA, wb_conv, conv_b, pe_out, 12544, 768, 768);
    assemble_kernel<<<37824, 256, 0, stream>>>(pe_out, cls_t, pos, h);

    // ---- transformer blocks ----
    for (int l = 0; l < 12; ++l) {
        cvt_layer_kernel<<<R_TOT / 4 / 256, 256, 0, stream>>>(
            qkv_w + (size_t)l * R_QKV, proj_w + (size_t)l * R_PRJ,
            fc1_w + (size_t)l * R_FC, fc2_w + (size_t)l * R_FC, wb_layer);
        ln_kernel<<<MTOK, 256, 0, stream>>>(h, 768, n1_s + l * 768, n1_b + l * 768, y);
        gemm_kernel<false, false, false><<<dim3(18, 99), 256, 0, stream>>>(
            y, wb_layer, qkv_b + l * 2304, qkvb, MTOK, 2304, 768);
        attn_kernel<<<768, 256, 0, stream>>>(qkvb, o);
        gemm_kernel<true, true, false><<<dim3(6, 99), 256, 0, stream>>>(
            o, wb_layer + R_QKV, proj_b + l * 768, h, MTOK, 768, 768);
        ln_kernel<<<MTOK, 256, 0, stream>>>(h, 768, n2_s + l * 768, n2_b + l * 768, y);
        gemm_kernel<false, false, true><<<dim3(24, 99), 256, 0, stream>>>(
            y, wb_layer + R_QKV + R_PRJ, fc1_b + l * 3072, mid, MTOK, 3072, 768);
        gemm_kernel<true, true, false><<<dim3(6, 99), 256, 0, stream>>>(
            mid, wb_layer + R_QKV + R_PRJ + R_FC, fc2_b + l * 768, h, MTOK, 768, 3072);
    }

    // ---- head: LN over cls tokens, then [64,768] x [1000,768]^T ----
    ln_kernel<<<64, 256, 0, stream>>>(h, NTOK * 768, enc_s, enc_b, yh);
    gemm_kernel<true, false, false><<<dim3(8, 1), 256, 0, stream>>>(
        yh, wb_head, head_b, (float*)d_out, 64, NCLS, 768);
}

// Round 2
// 6733.301 us; speedup vs baseline: 1.1960x; 1.1960x over previous
//
#include <hip/hip_runtime.h>
#include <hip/hip_bf16.h>

typedef __hip_bfloat16 bf16;
typedef __attribute__((ext_vector_type(8))) short bf16x8;
typedef __attribute__((ext_vector_type(4))) float f32x4;

#define B_SZ 64
#define D_MODEL 768
#define NTOK 197
#define MTOK (B_SZ * NTOK)      // 12608
#define NHEAD 12
#define HDIM 64
#define MLP_DIM 3072
#define NCLS 1000

// direct HBM -> LDS DMA, 16B per lane. LDS dest = l + lane*16 (HW-fixed).
__device__ __forceinline__ void g2l16(const bf16* g, bf16* l) {
    __builtin_amdgcn_global_load_lds(
        (const __attribute__((address_space(1))) void*)g,
        (__attribute__((address_space(3))) void*)l, 16, 0, 0);
}

// ---------------------------------------------------------------------------
// fp32 -> bf16 conversion (generic)
__global__ __launch_bounds__(256) void cvt_kernel(const float* __restrict__ in,
                                                  bf16* __restrict__ out, int n) {
    int i = ((int)blockIdx.x * 256 + (int)threadIdx.x) * 4;
    if (i >= n) return;
    float4 v = *(const float4*)(in + i);
    __align__(8) bf16 t[4] = {__float2bfloat16(v.x), __float2bfloat16(v.y),
                              __float2bfloat16(v.z), __float2bfloat16(v.w)};
    *(uint2*)(out + i) = *(uint2*)t;
}

// per-layer weight pack: qkv_w | proj_w | fc1_w | fc2_w  -> one bf16 buffer
#define R_QKV 1769472   // 2304*768
#define R_PRJ 589824    // 768*768
#define R_FC  2359296   // 3072*768
#define R_TOT 7077888
__global__ __launch_bounds__(256) void cvt_layer_kernel(
    const float* __restrict__ qw, const float* __restrict__ pw,
    const float* __restrict__ f1, const float* __restrict__ f2,
    bf16* __restrict__ out) {
    size_t i = ((size_t)blockIdx.x * 256 + threadIdx.x) * 4;   // < R_TOT
    const float* src;
    if (i < R_QKV)                src = qw + i;
    else if (i < R_QKV + R_PRJ)   src = pw + (i - R_QKV);
    else if (i < R_QKV + R_PRJ + R_FC) src = f1 + (i - R_QKV - R_PRJ);
    else                          src = f2 + (i - R_QKV - R_PRJ - R_FC);
    float4 v = *(const float4*)src;
    __align__(8) bf16 t[4] = {__float2bfloat16(v.x), __float2bfloat16(v.y),
                              __float2bfloat16(v.z), __float2bfloat16(v.w)};
    *(uint2*)(out + i) = *(uint2*)t;
}

// ---------------------------------------------------------------------------
// im2row for the patch-embed GEMM: x[B,3,224,224] -> A[12544][768] bf16
__global__ __launch_bounds__(256) void im2row_kernel(const float* __restrict__ x,
                                                     bf16* __restrict__ out) {
    size_t idx = (size_t)blockIdx.x * 256 + threadIdx.x;  // 12544*768 total
    int c = (int)(idx % 768);
    int r = (int)(idx / 768);
    int b = r / 196, pp = r % 196;
    int ph = pp / 14, pw = pp % 14;
    int ch = c >> 8, rem = c & 255;
    int i = rem >> 4, j = rem & 15;
    float v = x[(((size_t)b * 3 + ch) * 224 + ph * 16 + i) * 224 + pw * 16 + j];
    out[idx] = __float2bfloat16(v);
}

// assemble h[B,197,768] = concat(cls, patches) + pos
__global__ __launch_bounds__(256) void assemble_kernel(
    const float* __restrict__ pe, const float* __restrict__ cls,
    const float* __restrict__ pos, float* __restrict__ h) {
    size_t idx = (size_t)blockIdx.x * 256 + threadIdx.x;  // 64*197*768 total
    int d = (int)(idx % 768);
    size_t t_ = idx / 768;
    int t = (int)(t_ % 197);
    size_t b = t_ / 197;
    float v = (t == 0) ? cls[d] : pe[((size_t)b * 196 + (t - 1)) * 768 + d];
    h[idx] = v + pos[(size_t)t * 768 + d];
}

// ---------------------------------------------------------------------------
// LayerNorm over 768, one block per row. out is bf16 (GEMM A operand).
__global__ __launch_bounds__(256) void ln_kernel(
    const float* __restrict__ in, int row_stride,
    const float* __restrict__ sc, const float* __restrict__ bi,
    bf16* __restrict__ out) {
    const int row = blockIdx.x;
    const float* xr = in + (size_t)row * row_stride;
    const int tid = threadIdx.x;
    float v0 = xr[tid], v1 = xr[tid + 256], v2 = xr[tid + 512];
    float s = v0 + v1 + v2;
    float q = v0 * v0 + v1 * v1 + v2 * v2;
#pragma unroll
    for (int off = 32; off > 0; off >>= 1) {
        s += __shfl_down(s, off);
        q += __shfl_down(q, off);
    }
    __shared__ float sw[4], qw_[4];
    __shared__ float stat[2];
    int wv = tid >> 6;
    if ((tid & 63) == 0) { sw[wv] = s; qw_[wv] = q; }
    __syncthreads();
    if (tid == 0) {
        float S = sw[0] + sw[1] + sw[2] + sw[3];
        float Q = qw_[0] + qw_[1] + qw_[2] + qw_[3];
        float mean = S * (1.f / 768.f);
        float var = Q * (1.f / 768.f) - mean * mean;
        stat[0] = mean;
        stat[1] = rsqrtf(var + 1e-5f);
    }
    __syncthreads();
    float mean = stat[0], rstd = stat[1];
    size_t o0 = (size_t)row * 768;
    out[o0 + tid]       = __float2bfloat16((v0 - mean) * rstd * sc[tid]       + bi[tid]);
    out[o0 + tid + 256] = __float2bfloat16((v1 - mean) * rstd * sc[tid + 256] + bi[tid + 256]);
    out[o0 + tid + 512] = __float2bfloat16((v2 - mean) * rstd * sc[tid + 512] + bi[tid + 512]);
}

// ---------------------------------------------------------------------------
// Generic bf16 MFMA GEMM:  C[M,Nt] = A[M,K] * W[Nt,K]^T + bias, optional
// exact-erf GELU, optional fp32 residual accumulate.
// 128x128 tile, BK=64, 256 threads (2x2 waves of 64x64, 4x4 16x16x32 mfma).
// Staging: global_load_lds 16B/lane (m97 ladder step). The LDS image equals
// the XOR-swizzled layout of round 1 (chunk (i&7)^(i>>3) fetched per lane),
// so fragment ds_read_b128s stay conflict-free (SQ_LDS_BANK_CONFLICT==0).
template <bool OUT_F32, bool RESID, bool GELU>
__global__ __launch_bounds__(256) void gemm_kernel(
    const bf16* __restrict__ A, const bf16* __restrict__ W,
    const float* __restrict__ bias, void* __restrict__ Cout,
    int M, int Nt, int K) {
    __shared__ __align__(16) bf16 As[128 * 64];
    __shared__ __align__(16) bf16 Bs[128 * 64];
    const int tid = threadIdx.x;
    const int lane = tid & 63;
    const int wave = tid >> 6;
    const int wm = wave >> 1, wn = wave & 1;
    const int m0 = blockIdx.y * 128, n0 = blockIdx.x * 128;
    const int m16 = lane & 15, kg = lane >> 4;

    f32x4 acc[4][4] = {};

    // staging geometry: each wave owns 32 rows of As and Bs (4 chunks of 8).
    // lane -> row offset (lane>>3), swizzled col chunk ((lane&7)^(lane>>3)).
    const int lr = lane >> 3;
    const int lc = ((lane & 7) ^ lr) * 8;          // element offset in row
    const bf16* aptr[4];
    const bf16* bptr[4];
    bf16* alds[4];
    bf16* blds[4];
#pragma unroll
    for (int c = 0; c < 4; ++c) {
        int rsub = wave * 32 + c * 8;
        int ra = m0 + rsub + lr; ra = ra < M ? ra : M - 1;    // clamp: no OOB
        int rb = n0 + rsub + lr; rb = rb < Nt ? rb : Nt - 1;
        aptr[c] = A + (size_t)ra * K + lc;
        bptr[c] = W + (size_t)rb * K + lc;
        alds[c] = &As[rsub * 64];
        blds[c] = &Bs[rsub * 64];
    }

    for (int k0 = 0; k0 < K; k0 += 64) {
        __syncthreads();
#pragma unroll
        for (int c = 0; c < 4; ++c) g2l16(aptr[c] + k0, alds[c]);
#pragma unroll
        for (int c = 0; c < 4; ++c) g2l16(bptr[c] + k0, blds[c]);
        __syncthreads();
#pragma unroll
        for (int ks = 0; ks < 2; ++ks) {
            bf16x8 af[4], bfv[4];
            const int ch = ((ks << 2) + kg) ^ (m16 & 7);
#pragma unroll
            for (int t = 0; t < 4; ++t)
                af[t] = *(const bf16x8*)&As[(wm * 64 + t * 16 + m16) * 64 + (ch << 3)];
#pragma unroll
            for (int t = 0; t < 4; ++t)
                bfv[t] = *(const bf16x8*)&Bs[(wn * 64 + t * 16 + m16) * 64 + (ch << 3)];
#pragma unroll
            for (int i = 0; i < 4; ++i)
#pragma unroll
                for (int j = 0; j < 4; ++j)
                    acc[i][j] = __builtin_amdgcn_mfma_f32_16x16x32_bf16(
                        af[i], bfv[j], acc[i][j], 0, 0, 0);
        }
    }
    // epilogue: C/D layout col=lane&15, row=quad*4+reg  [m89-verified]
    const int quad = lane >> 4;
#pragma unroll
    for (int i = 0; i < 4; ++i) {
        const int rbase = m0 + wm * 64 + i * 16 + quad * 4;
#pragma unroll
        for (int j = 0; j < 4; ++j) {
            const int col = n0 + wn * 64 + j * 16 + m16;
            if (col >= Nt) continue;
            const float bv = bias[col];
#pragma unroll
            for (int r = 0; r < 4; ++r) {
                const int row = rbase + r;
                if (row >= M) continue;
                float v = acc[i][j][r] + bv;
                if (GELU) v = 0.5f * v * (1.f + erff(v * 0.7071067811865476f));
                if (OUT_F32) {
                    float* op = (float*)Cout + (size_t)row * Nt + col;
                    if (RESID) *op += v; else *op = v;
                } else {
                    ((bf16*)Cout)[(size_t)row * Nt + col] = __float2bfloat16(v);
                }
            }
        }
    }
}

// ---------------------------------------------------------------------------
// Fused attention. One block per (b, head). K,V staged in LDS once; loop over
// 7 Q-tiles of 32 rows: S = Q K^T (mfma) -> LDS fp32 -> softmax -> P bf16 in
// A-operand layout -> O = P V (mfma) -> store o[b,i, h*64+d].
__global__ __launch_bounds__(256) void attn_kernel(const bf16* __restrict__ qkv,
                                                   bf16* __restrict__ o) {
    __shared__ __align__(16) bf16 Ks[208 * 72];   // K rows (j), stride 72 (conflict-free)
    __shared__ __align__(16) bf16 Vt[64 * 232];   // V^T: row=d, col=j, stride 232
    __shared__ __align__(16) bf16 Qs[32 * 72];
    __shared__ float Ss[32 * 209];
    __shared__ __align__(16) bf16 Ps[32 * 232];

    const int tid = threadIdx.x, lane = tid & 63, wave = tid >> 6;
    const int b = blockIdx.x / NHEAD, hh = blockIdx.x % NHEAD;
    const size_t base = (size_t)b * NTOK * 2304 + hh * 64;
    const int m16 = lane & 15, kg = lane >> 4, quad = lane >> 4;

    {  // stage K and V (transposed), zero-pad j in [197,224)
        const int jr = tid >> 3, ds = tid & 7;
        for (int j0 = 0; j0 < 224; j0 += 32) {
            int j = j0 + jr;
            if (j < 197) {
                int4 kv = *(const int4*)(qkv + base + 768 + (size_t)j * 2304 + ds * 8);
                *(int4*)&Ks[j * 72 + ds * 8] = kv;
                __align__(16) bf16 tmp[8];
                *(int4*)tmp = *(const int4*)(qkv + base + 1536 + (size_t)j * 2304 + ds * 8);
#pragma unroll
                for (int u = 0; u < 8; ++u) Vt[(ds * 8 + u) * 232 + j] = tmp[u];
            } else {
                if (j < 208) {
                    int4 z = make_int4(0, 0, 0, 0);
                    *(int4*)&Ks[j * 72 + ds * 8] = z;
                }
                bf16 zb = __float2bfloat16(0.f);
#pragma unroll
                for (int u = 0; u < 8; ++u) Vt[(ds * 8 + u) * 232 + j] = zb;
            }
        }
    }
    __syncthreads();

    for (int qt = 0; qt < 7; ++qt) {
        {  // stage 32 Q rows (zeros past token 196)
            const int r = tid >> 3, ds = tid & 7;
            int qi = qt * 32 + r;
            int4 v = make_int4(0, 0, 0, 0);
            if (qi < 197) v = *(const int4*)(qkv + base + (size_t)qi * 2304 + ds * 8);
            *(int4*)&Qs[r * 72 + ds * 8] = v;
        }
        __syncthreads();
        // S = Q K^T * scale ; wave w covers n-tiles w, w+4, ...
        bf16x8 qf[2][2];
#pragma unroll
        for (int mt = 0; mt < 2; ++mt)
#pragma unroll
            for (int ks = 0; ks < 2; ++ks)
                qf[mt][ks] = *(const bf16x8*)&Qs[(mt * 16 + m16) * 72 + ks * 32 + kg * 8];
        for (int nt = wave; nt < 13; nt += 4) {
            f32x4 s0 = {0.f, 0.f, 0.f, 0.f}, s1 = {0.f, 0.f, 0.f, 0.f};
#pragma unroll
            for (int ks = 0; ks < 2; ++ks) {
                bf16x8 kf = *(const bf16x8*)&Ks[(nt * 16 + m16) * 72 + ks * 32 + kg * 8];
                s0 = __builtin_amdgcn_mfma_f32_16x16x32_bf16(qf[0][ks], kf, s0, 0, 0, 0);
                s1 = __builtin_amdgcn_mfma_f32_16x16x32_bf16(qf[1][ks], kf, s1, 0, 0, 0);
            }
            const int col = nt * 16 + m16;
#pragma unroll
            for (int r = 0; r < 4; ++r) {
                Ss[(quad * 4 + r) * 209 + col]        = s0[r] * 0.125f;
                Ss[(16 + quad * 4 + r) * 209 + col]   = s1[r] * 0.125f;
            }
        }
        __syncthreads();
        {  // softmax: 8 threads per row
            const int r = tid >> 3, c0 = tid & 7;
            const float* srow = &Ss[r * 209];
            float mx = -3.0e38f;
            for (int c = c0; c < 197; c += 8) mx = fmaxf(mx, srow[c]);
#pragma unroll
            for (int off = 4; off > 0; off >>= 1) mx = fmaxf(mx, __shfl_xor(mx, off, 8));
            float l = 0.f;
            for (int c = c0; c < 197; c += 8) l += __expf(srow[c] - mx);
#pragma unroll
            for (int off = 4; off > 0; off >>= 1) l += __shfl_xor(l, off, 8);
            const float inv = 1.f / l;
            bf16* prow = &Ps[r * 232];
            for (int c = c0; c < 224; c += 8)
                prow[c] = __float2bfloat16(c < 197 ? __expf(srow[c] - mx) * inv : 0.f);
        }
        __syncthreads();
        // O = P V ; wave w owns d-tile w (16 d's)
        f32x4 o0 = {0.f, 0.f, 0.f, 0.f}, o1 = {0.f, 0.f, 0.f, 0.f};
#pragma unroll
        for (int ks = 0; ks < 7; ++ks) {
            bf16x8 vf = *(const bf16x8*)&Vt[(wave * 16 + m16) * 232 + ks * 32 + kg * 8];
            bf16x8 p0 = *(const bf16x8*)&Ps[m16 * 232 + ks * 32 + kg * 8];
            bf16x8 p1 = *(const bf16x8*)&Ps[(16 + m16) * 232 + ks * 32 + kg * 8];
            o0 = __builtin_amdgcn_mfma_f32_16x16x32_bf16(p0, vf, o0, 0, 0, 0);
            o1 = __builtin_amdgcn_mfma_f32_16x16x32_bf16(p1, vf, o1, 0, 0, 0);
        }
        const int dcol = hh * 64 + wave * 16 + m16;
#pragma unroll
        for (int r = 0; r < 4; ++r) {
            int q0i = qt * 32 + quad * 4 + r;
            if (q0i < 197) o[((size_t)b * NTOK + q0i) * 768 + dcol] = __float2bfloat16(o0[r]);
            int q1i = qt * 32 + 16 + quad * 4 + r;
            if (q1i < 197) o[((size_t)b * NTOK + q1i) * 768 + dcol] = __float2bfloat16(o1[r]);
        }
    }
}

// ---------------------------------------------------------------------------
extern "C" void kernel_launch(void* const* d_in, const int* in_sizes, int n_in,
                              void* d_out, int out_size, void* d_ws, size_t ws_size,
                              hipStream_t stream) {
    const float* x      = (const float*)d_in[0];
    const float* conv_w = (const float*)d_in[1];
    const float* conv_b = (const float*)d_in[2];
    const float* cls_t  = (const float*)d_in[3];
    const float* pos    = (const float*)d_in[4];
    const float* qkv_w  = (const float*)d_in[5];
    const float* qkv_b  = (const float*)d_in[6];
    const float* proj_w = (const float*)d_in[7];
    const float* proj_b = (const float*)d_in[8];
    const float* n1_s   = (const float*)d_in[9];
    const float* n1_b   = (const float*)d_in[10];
    const float* n2_s   = (const float*)d_in[11];
    const float* n2_b   = (const float*)d_in[12];
    const float* fc1_w  = (const float*)d_in[13];
    const float* fc1_b  = (const float*)d_in[14];
    const float* fc2_w  = (const float*)d_in[15];
    const float* fc2_b  = (const float*)d_in[16];
    const float* enc_s  = (const float*)d_in[17];
    const float* enc_b  = (const float*)d_in[18];
    const float* head_w = (const float*)d_in[19];
    const float* head_b = (const float*)d_in[20];

    char* p = (char*)d_ws;
    auto take = [&](size_t bytes) -> char* {
        char* r = p;
        p += (bytes + 255) & ~(size_t)255;
        return r;
    };
    bf16* wb_layer = (bf16*)take((size_t)R_TOT * 2);            // 14.2 MB, reused per layer
    bf16* wb_conv  = (bf16*)take((size_t)589824 * 2);
    bf16* wb_head  = (bf16*)take((size_t)NCLS * 768 * 2);
    float* h       = (float*)take((size_t)MTOK * 768 * 4);      // residual stream, fp32
    bf16* y        = (bf16*)take((size_t)MTOK * 768 * 2);       // LN output
    char* qkv_raw  = take((size_t)MTOK * 2304 * 2);
    bf16* qkvb     = (bf16*)qkv_raw;
    float* pe_out  = (float*)qkv_raw;                           // alias (used pre-loop only)
    bf16* o        = (bf16*)take((size_t)MTOK * 768 * 2);
    char* mid_raw  = take((size_t)MTOK * 3072 * 2);
    bf16* mid      = (bf16*)mid_raw;
    bf16* peA      = (bf16*)mid_raw;                            // alias (used pre-loop only)
    bf16* yh       = (bf16*)take((size_t)128 * 768 * 2);        // padded to 128 rows

    // ---- patch embed ----
    cvt_kernel<<<576, 256, 0, stream>>>(conv_w, wb_conv, 589824);
    cvt_kernel<<<750, 256, 0, stream>>>(head_w, wb_head, NCLS * 768);
    im2row_kernel<<<37632, 256, 0, stream>>>(x, peA);
    gemm_kernel<true, false, false><<<dim3(6, 98), 256, 0, stream>>>(
        peA, wb_conv, conv_b, pe_out, 12544, 768, 768);
    assemble_kernel<<<37824, 256, 0, stream>>>(pe_out, cls_t, pos, h);

    // ---- transformer blocks ----
    for (int l = 0; l < 12; ++l) {
        cvt_layer_kernel<<<R_TOT / 4 / 256, 256, 0, stream>>>(
            qkv_w + (size_t)l * R_QKV, proj_w + (size_t)l * R_PRJ,
            fc1_w + (size_t)l * R_FC, fc2_w + (size_t)l * R_FC, wb_layer);
        ln_kernel<<<MTOK, 256, 0, stream>>>(h, 768, n1_s + l * 768, n1_b + l * 768, y);
        gemm_kernel<false, false, false><<<dim3(18, 99), 256, 0, stream>>>(
            y, wb_layer, qkv_b + l * 2304, qkvb, MTOK, 2304, 768);
        attn_kernel<<<768, 256, 0, stream>>>(qkvb, o);
        gemm_kernel<true, true, false><<<dim3(6, 99), 256, 0, stream>>>(
            o, wb_layer + R_QKV, proj_b + l * 768, h, MTOK, 768, 768);
        ln_kernel<<<MTOK, 256, 0, stream>>>(h, 768, n2_s + l * 768, n2_b + l * 768, y);
        gemm_kernel<false, false, true><<<dim3(24, 99), 256, 0, stream>>>(
            y, wb_layer + R_QKV + R_PRJ, fc1_b + l * 3072, mid, MTOK, 3072, 768);
        gemm_kernel<true, true, false><<<dim3(6, 99), 256, 0, stream>>>(
            mid, wb_layer + R_QKV + R_PRJ + R_FC, fc2_b + l * 768, h, MTOK, 768, 3072);
    }

    // ---- head: LN over cls tokens, then [64,768] x [1000,768]^T ----
    ln_kernel<<<64, 256, 0, stream>>>(h, NTOK * 768, enc_s, enc_b, yh);
    gemm_kernel<true, false, false><<<dim3(8, 1), 256, 0, stream>>>(
        yh, wb_head, head_b, (float*)d_out, 64, NCLS, 768);
}

// Round 3
// 6057.586 us; speedup vs baseline: 1.3294x; 1.1115x over previous
//
#include <hip/hip_runtime.h>
#include <hip/hip_bf16.h>

typedef __hip_bfloat16 bf16;
typedef __attribute__((ext_vector_type(8))) short bf16x8;
typedef __attribute__((ext_vector_type(4))) float f32x4;

#define B_SZ 64
#define D_MODEL 768
#define NTOK 197
#define MTOK (B_SZ * NTOK)      // 12608
#define NHEAD 12
#define HDIM 64
#define MLP_DIM 3072
#define NCLS 1000

// direct HBM -> LDS DMA, 16B per lane. LDS dest = base + lane*16 (HW-fixed).
__device__ __forceinline__ void g2l16(const bf16* g, bf16* l) {
    __builtin_amdgcn_global_load_lds(
        (const __attribute__((address_space(1))) void*)g,
        (__attribute__((address_space(3))) void*)l, 16, 0, 0);
}

// ---------------------------------------------------------------------------
// fp32 -> bf16 conversion (generic)
__global__ __launch_bounds__(256) void cvt_kernel(const float* __restrict__ in,
                                                  bf16* __restrict__ out, int n) {
    int i = ((int)blockIdx.x * 256 + (int)threadIdx.x) * 4;
    if (i >= n) return;
    float4 v = *(const float4*)(in + i);
    __align__(8) bf16 t[4] = {__float2bfloat16(v.x), __float2bfloat16(v.y),
                              __float2bfloat16(v.z), __float2bfloat16(v.w)};
    *(uint2*)(out + i) = *(uint2*)t;
}

// per-layer weight pack: qkv_w | proj_w | fc1_w | fc2_w  -> one bf16 buffer
#define R_QKV 1769472   // 2304*768
#define R_PRJ 589824    // 768*768
#define R_FC  2359296   // 3072*768
#define R_TOT 7077888
__global__ __launch_bounds__(256) void cvt_layer_kernel(
    const float* __restrict__ qw, const float* __restrict__ pw,
    const float* __restrict__ f1, const float* __restrict__ f2,
    bf16* __restrict__ out) {
    size_t i = ((size_t)blockIdx.x * 256 + threadIdx.x) * 4;   // < R_TOT
    const float* src;
    if (i < R_QKV)                src = qw + i;
    else if (i < R_QKV + R_PRJ)   src = pw + (i - R_QKV);
    else if (i < R_QKV + R_PRJ + R_FC) src = f1 + (i - R_QKV - R_PRJ);
    else                          src = f2 + (i - R_QKV - R_PRJ - R_FC);
    float4 v = *(const float4*)src;
    __align__(8) bf16 t[4] = {__float2bfloat16(v.x), __float2bfloat16(v.y),
                              __float2bfloat16(v.z), __float2bfloat16(v.w)};
    *(uint2*)(out + i) = *(uint2*)t;
}

// ---------------------------------------------------------------------------
// im2row for the patch-embed GEMM: x[B,3,224,224] -> A[12544][768] bf16
__global__ __launch_bounds__(256) void im2row_kernel(const float* __restrict__ x,
                                                     bf16* __restrict__ out) {
    size_t idx = (size_t)blockIdx.x * 256 + threadIdx.x;  // 12544*768 total
    int c = (int)(idx % 768);
    int r = (int)(idx / 768);
    int b = r / 196, pp = r % 196;
    int ph = pp / 14, pw = pp % 14;
    int ch = c >> 8, rem = c & 255;
    int i = rem >> 4, j = rem & 15;
    float v = x[(((size_t)b * 3 + ch) * 224 + ph * 16 + i) * 224 + pw * 16 + j];
    out[idx] = __float2bfloat16(v);
}

// assemble h[B,197,768] = concat(cls, patches) + pos
__global__ __launch_bounds__(256) void assemble_kernel(
    const float* __restrict__ pe, const float* __restrict__ cls,
    const float* __restrict__ pos, float* __restrict__ h) {
    size_t idx = (size_t)blockIdx.x * 256 + threadIdx.x;  // 64*197*768 total
    int d = (int)(idx % 768);
    size_t t_ = idx / 768;
    int t = (int)(t_ % 197);
    size_t b = t_ / 197;
    float v = (t == 0) ? cls[d] : pe[((size_t)b * 196 + (t - 1)) * 768 + d];
    h[idx] = v + pos[(size_t)t * 768 + d];
}

// ---------------------------------------------------------------------------
// LayerNorm over 768, one block per row. out is bf16 (GEMM A operand).
__global__ __launch_bounds__(256) void ln_kernel(
    const float* __restrict__ in, int row_stride,
    const float* __restrict__ sc, const float* __restrict__ bi,
    bf16* __restrict__ out) {
    const int row = blockIdx.x;
    const float* xr = in + (size_t)row * row_stride;
    const int tid = threadIdx.x;
    float v0 = xr[tid], v1 = xr[tid + 256], v2 = xr[tid + 512];
    float s = v0 + v1 + v2;
    float q = v0 * v0 + v1 * v1 + v2 * v2;
#pragma unroll
    for (int off = 32; off > 0; off >>= 1) {
        s += __shfl_down(s, off);
        q += __shfl_down(q, off);
    }
    __shared__ float sw[4], qw_[4];
    __shared__ float stat[2];
    int wv = tid >> 6;
    if ((tid & 63) == 0) { sw[wv] = s; qw_[wv] = q; }
    __syncthreads();
    if (tid == 0) {
        float S = sw[0] + sw[1] + sw[2] + sw[3];
        float Q = qw_[0] + qw_[1] + qw_[2] + qw_[3];
        float mean = S * (1.f / 768.f);
        float var = Q * (1.f / 768.f) - mean * mean;
        stat[0] = mean;
        stat[1] = rsqrtf(var + 1e-5f);
    }
    __syncthreads();
    float mean = stat[0], rstd = stat[1];
    size_t o0 = (size_t)row * 768;
    out[o0 + tid]       = __float2bfloat16((v0 - mean) * rstd * sc[tid]       + bi[tid]);
    out[o0 + tid + 256] = __float2bfloat16((v1 - mean) * rstd * sc[tid + 256] + bi[tid + 256]);
    out[o0 + tid + 512] = __float2bfloat16((v2 - mean) * rstd * sc[tid + 512] + bi[tid + 512]);
}

// ---------------------------------------------------------------------------
// Generic bf16 MFMA GEMM (m97-class: global_load_lds staging, XOR swizzle).
template <bool OUT_F32, bool RESID, bool GELU>
__global__ __launch_bounds__(256) void gemm_kernel(
    const bf16* __restrict__ A, const bf16* __restrict__ W,
    const float* __restrict__ bias, void* __restrict__ Cout,
    int M, int Nt, int K) {
    __shared__ __align__(16) bf16 As[128 * 64];
    __shared__ __align__(16) bf16 Bs[128 * 64];
    const int tid = threadIdx.x;
    const int lane = tid & 63;
    const int wave = tid >> 6;
    const int wm = wave >> 1, wn = wave & 1;
    const int m0 = blockIdx.y * 128, n0 = blockIdx.x * 128;
    const int m16 = lane & 15, kg = lane >> 4;

    f32x4 acc[4][4] = {};

    const int lr = lane >> 3;
    const int lc = ((lane & 7) ^ lr) * 8;          // swizzled chunk in row
    const bf16* aptr[4];
    const bf16* bptr[4];
    bf16* alds[4];
    bf16* blds[4];
#pragma unroll
    for (int c = 0; c < 4; ++c) {
        int rsub = wave * 32 + c * 8;
        int ra = m0 + rsub + lr; ra = ra < M ? ra : M - 1;    // clamp: no OOB
        int rb = n0 + rsub + lr; rb = rb < Nt ? rb : Nt - 1;
        aptr[c] = A + (size_t)ra * K + lc;
        bptr[c] = W + (size_t)rb * K + lc;
        alds[c] = &As[rsub * 64];
        blds[c] = &Bs[rsub * 64];
    }

    for (int k0 = 0; k0 < K; k0 += 64) {
        __syncthreads();
#pragma unroll
        for (int c = 0; c < 4; ++c) g2l16(aptr[c] + k0, alds[c]);
#pragma unroll
        for (int c = 0; c < 4; ++c) g2l16(bptr[c] + k0, blds[c]);
        __syncthreads();
#pragma unroll
        for (int ks = 0; ks < 2; ++ks) {
            bf16x8 af[4], bfv[4];
            const int ch = ((ks << 2) + kg) ^ (m16 & 7);
#pragma unroll
            for (int t = 0; t < 4; ++t)
                af[t] = *(const bf16x8*)&As[(wm * 64 + t * 16 + m16) * 64 + (ch << 3)];
#pragma unroll
            for (int t = 0; t < 4; ++t)
                bfv[t] = *(const bf16x8*)&Bs[(wn * 64 + t * 16 + m16) * 64 + (ch << 3)];
#pragma unroll
            for (int i = 0; i < 4; ++i)
#pragma unroll
                for (int j = 0; j < 4; ++j)
                    acc[i][j] = __builtin_amdgcn_mfma_f32_16x16x32_bf16(
                        af[i], bfv[j], acc[i][j], 0, 0, 0);
        }
    }
    const int quad = lane >> 4;
#pragma unroll
    for (int i = 0; i < 4; ++i) {
        const int rbase = m0 + wm * 64 + i * 16 + quad * 4;
#pragma unroll
        for (int j = 0; j < 4; ++j) {
            const int col = n0 + wn * 64 + j * 16 + m16;
            if (col >= Nt) continue;
            const float bv = bias[col];
#pragma unroll
            for (int r = 0; r < 4; ++r) {
                const int row = rbase + r;
                if (row >= M) continue;
                float v = acc[i][j][r] + bv;
                if (GELU) v = 0.5f * v * (1.f + erff(v * 0.7071067811865476f));
                if (OUT_F32) {
                    float* op = (float*)Cout + (size_t)row * Nt + col;
                    if (RESID) *op += v; else *op = v;
                } else {
                    ((bf16*)Cout)[(size_t)row * Nt + col] = __float2bfloat16(v);
                }
            }
        }
    }
}

// ---------------------------------------------------------------------------
// V transpose: qkvb V-part -> vT[bh][64][224] (j padded to 224 with zeros).
// One block per (bh, j-block of 64). LDS tile 64x64 (stride 72).
__global__ __launch_bounds__(256) void trv_kernel(const bf16* __restrict__ qkv,
                                                  bf16* __restrict__ vT) {
    __shared__ __align__(16) bf16 T[64 * 72];
    const int tid = threadIdx.x;
    const int bh = blockIdx.x >> 2;
    const int j0 = (blockIdx.x & 3) * 64;
    const int b = bh / NHEAD, hh = bh % NHEAD;
    const size_t vbase = (size_t)b * NTOK * 2304 + 1536 + (size_t)hh * 64;
    {
        int j = tid >> 2;
        int jj = j0 + j;
        int cpair = (tid & 3) * 2;
#pragma unroll
        for (int cc = 0; cc < 2; ++cc) {
            int c = cpair + cc;
            int4 v = make_int4(0, 0, 0, 0);
            if (jj < 197) v = *(const int4*)(qkv + vbase + (size_t)jj * 2304 + c * 8);
            *(int4*)&T[j * 72 + c * 8] = v;
        }
    }
    __syncthreads();
    {
        int d = tid >> 2;
#pragma unroll
        for (int cc = 0; cc < 2; ++cc) {
            int lch = (tid & 3) + cc * 4;     // local 16B chunk (8 j's)
            __align__(16) bf16 tmp[8];
#pragma unroll
            for (int u = 0; u < 8; ++u) tmp[u] = T[(lch * 8 + u) * 72 + d];
            *(int4*)(vT + ((size_t)bh * 64 + d) * 224 + j0 + lch * 8) = *(int4*)tmp;
        }
    }
}

// ---------------------------------------------------------------------------
// Fused attention, round-3: in-register softmax (no Ss), K and V^T staged via
// global_load_lds into XOR-swizzled LDS. 80,896 B LDS -> 2 blocks/CU.
__global__ __launch_bounds__(256) void attn_kernel(const bf16* __restrict__ qkv,
                                                   const bf16* __restrict__ vT,
                                                   bf16* __restrict__ o) {
    __shared__ __align__(16) bf16 Ks[208 * 64];   // swizzled rows of 64
    __shared__ __align__(16) bf16 Vt[64 * 256];   // V^T rows (d), swizzled, stride 256
    __shared__ __align__(16) bf16 Qs[32 * 64];    // swizzled
    __shared__ __align__(16) bf16 Ps[32 * 256];   // P in A-layout, swizzled
    __shared__ float pmax[4][32];
    __shared__ float psum[4][32];

    const int tid = threadIdx.x, lane = tid & 63, wave = tid >> 6;
    const int bh = blockIdx.x;
    const int b = bh / NHEAD, hh = bh % NHEAD;
    const size_t base = (size_t)b * NTOK * 2304 + hh * 64;
    const int m16 = lane & 15, kg = lane >> 4, quad = lane >> 4;

    // ---- one-time staging ----
    {
        // K rows 0..196 via DMA (prefix-masked tail group), swizzled chunks
        const int lr = lane >> 3, lc7 = lane & 7;
        for (int g = wave; g < 25; g += 4) {
            int row = g * 8 + lr;
            if (row < 197)
                g2l16(qkv + base + 768 + (size_t)row * 2304 + ((lc7 ^ lr) * 8),
                      &Ks[g * 512]);
        }
        // zero K rows 197..207 (88 int4)
        if (tid < 88) {
            int row = 197 + tid / 8, ch = tid % 8;
            *(int4*)&Ks[row * 64 + ch * 8] = make_int4(0, 0, 0, 0);
        }
        // zero Ps logical chunks 26..27 (cols 208..223, never written later)
        if (tid < 64) {
            int row = tid >> 1, c = 26 + (tid & 1);
            *(int4*)&Ps[row * 256 + ((c ^ (row & 7)) * 8)] = make_int4(0, 0, 0, 0);
        }
        // V^T via DMA: 2 rows per wave-op; clamp invalid logical chunks into
        // never-read physical slots (all lanes active -> unambiguous layout)
        const int vr = lane >> 5, vp = lane & 31;
        for (int g = wave; g < 32; g += 4) {
            int row = g * 2 + vr;
            int c = vp ^ (row & 7);
            int cc = c < 28 ? c : 27;
            g2l16(vT + ((size_t)bh * 64 + row) * 224 + cc * 8, &Vt[g * 512]);
        }
    }
    __syncthreads();

    for (int qt = 0; qt < 7; ++qt) {
        {  // stage 32 Q rows (VGPR roundtrip, zero-fill, swizzled)
            int r = tid >> 3, c = tid & 7;
            int qi = qt * 32 + r;
            int4 v = make_int4(0, 0, 0, 0);
            if (qi < 197) v = *(const int4*)(qkv + base + (size_t)qi * 2304 + c * 8);
            *(int4*)&Qs[r * 64 + ((c ^ (r & 7)) * 8)] = v;
        }
        __syncthreads();

        bf16x8 qf[2][2];
#pragma unroll
        for (int mt = 0; mt < 2; ++mt)
#pragma unroll
            for (int ks = 0; ks < 2; ++ks)
                qf[mt][ks] = *(const bf16x8*)
                    &Qs[(mt * 16 + m16) * 64 + (((ks * 4 + kg) ^ (m16 & 7)) * 8)];

        // S = Q K^T : wave w owns n-tiles w, w+4, w+8, w+12(<13)
        f32x4 sacc[2][4];
#pragma unroll
        for (int mt = 0; mt < 2; ++mt)
#pragma unroll
            for (int t = 0; t < 4; ++t) sacc[mt][t] = (f32x4){0.f, 0.f, 0.f, 0.f};
#pragma unroll
        for (int t = 0; t < 4; ++t) {
            int nt = wave + 4 * t;
            if (nt < 13) {
#pragma unroll
                for (int ks = 0; ks < 2; ++ks) {
                    bf16x8 kf = *(const bf16x8*)
                        &Ks[(nt * 16 + m16) * 64 + (((ks * 4 + kg) ^ (m16 & 7)) * 8)];
                    sacc[0][t] = __builtin_amdgcn_mfma_f32_16x16x32_bf16(
                        qf[0][ks], kf, sacc[0][t], 0, 0, 0);
                    sacc[1][t] = __builtin_amdgcn_mfma_f32_16x16x32_bf16(
                        qf[1][ks], kf, sacc[1][t], 0, 0, 0);
                }
            }
        }
        // ---- in-register softmax (C-layout: row = quad*4+r, col = nt*16+m16)
        float pm[2][4];
#pragma unroll
        for (int mt = 0; mt < 2; ++mt)
#pragma unroll
            for (int r = 0; r < 4; ++r) pm[mt][r] = -3.0e38f;
#pragma unroll
        for (int t = 0; t < 4; ++t) {
            int nt = wave + 4 * t;
            bool v = (nt * 16 + m16) < 197;
#pragma unroll
            for (int mt = 0; mt < 2; ++mt)
#pragma unroll
                for (int r = 0; r < 4; ++r) {
                    float x = sacc[mt][t][r] * 0.125f;
                    sacc[mt][t][r] = x;
                    if (v) pm[mt][r] = fmaxf(pm[mt][r], x);
                }
        }
#pragma unroll
        for (int off = 1; off < 16; off <<= 1)
#pragma unroll
            for (int mt = 0; mt < 2; ++mt)
#pragma unroll
                for (int r = 0; r < 4; ++r)
                    pm[mt][r] = fmaxf(pm[mt][r], __shfl_xor(pm[mt][r], off));
        if (m16 == 0) {
#pragma unroll
            for (int mt = 0; mt < 2; ++mt)
#pragma unroll
                for (int r = 0; r < 4; ++r)
                    pmax[wave][mt * 16 + quad * 4 + r] = pm[mt][r];
        }
        __syncthreads();
        float fm[2][4];
#pragma unroll
        for (int mt = 0; mt < 2; ++mt)
#pragma unroll
            for (int r = 0; r < 4; ++r) {
                int row = mt * 16 + quad * 4 + r;
                fm[mt][r] = fmaxf(fmaxf(pmax[0][row], pmax[1][row]),
                                  fmaxf(pmax[2][row], pmax[3][row]));
            }
        float ps[2][4] = {};
#pragma unroll
        for (int t = 0; t < 4; ++t) {
            int nt = wave + 4 * t;
            bool v = (nt * 16 + m16) < 197;
#pragma unroll
            for (int mt = 0; mt < 2; ++mt)
#pragma unroll
                for (int r = 0; r < 4; ++r) {
                    float e = v ? __expf(sacc[mt][t][r] - fm[mt][r]) : 0.f;
                    sacc[mt][t][r] = e;
                    ps[mt][r] += e;
                }
        }
#pragma unroll
        for (int off = 1; off < 16; off <<= 1)
#pragma unroll
            for (int mt = 0; mt < 2; ++mt)
#pragma unroll
                for (int r = 0; r < 4; ++r)
                    ps[mt][r] += __shfl_xor(ps[mt][r], off);
        if (m16 == 0) {
#pragma unroll
            for (int mt = 0; mt < 2; ++mt)
#pragma unroll
                for (int r = 0; r < 4; ++r)
                    psum[wave][mt * 16 + quad * 4 + r] = ps[mt][r];
        }
        __syncthreads();
        float inv[2][4];
#pragma unroll
        for (int mt = 0; mt < 2; ++mt)
#pragma unroll
            for (int r = 0; r < 4; ++r) {
                int row = mt * 16 + quad * 4 + r;
                inv[mt][r] = 1.f / (psum[0][row] + psum[1][row] +
                                    psum[2][row] + psum[3][row]);
            }
        // write P (bf16) into swizzled A-layout
#pragma unroll
        for (int t = 0; t < 4; ++t) {
            int nt = wave + 4 * t;
            int col = nt * 16 + m16;
            if (col < 208) {
#pragma unroll
                for (int mt = 0; mt < 2; ++mt)
#pragma unroll
                    for (int r = 0; r < 4; ++r) {
                        int row = mt * 16 + quad * 4 + r;
                        Ps[row * 256 + (((col >> 3) ^ (row & 7)) * 8) + (col & 7)] =
                            __float2bfloat16(sacc[mt][t][r] * inv[mt][r]);
                    }
            }
        }
        __syncthreads();
        // O = P V : wave w owns d-tile w
        f32x4 o0 = {0.f, 0.f, 0.f, 0.f}, o1 = {0.f, 0.f, 0.f, 0.f};
        const int vrow = wave * 16 + m16;
#pragma unroll
        for (int ks = 0; ks < 7; ++ks) {
            bf16x8 vf = *(const bf16x8*)
                &Vt[vrow * 256 + (((ks * 4 + kg) ^ (vrow & 7)) * 8)];
            bf16x8 p0 = *(const bf16x8*)
                &Ps[m16 * 256 + (((ks * 4 + kg) ^ (m16 & 7)) * 8)];
            bf16x8 p1 = *(const bf16x8*)
                &Ps[(16 + m16) * 256 + (((ks * 4 + kg) ^ (m16 & 7)) * 8)];
            o0 = __builtin_amdgcn_mfma_f32_16x16x32_bf16(p0, vf, o0, 0, 0, 0);
            o1 = __builtin_amdgcn_mfma_f32_16x16x32_bf16(p1, vf, o1, 0, 0, 0);
        }
        const int dcol = hh * 64 + wave * 16 + m16;
#pragma unroll
        for (int r = 0; r < 4; ++r) {
            int q0i = qt * 32 + quad * 4 + r;
            if (q0i < 197) o[((size_t)b * NTOK + q0i) * 768 + dcol] = __float2bfloat16(o0[r]);
            int q1i = qt * 32 + 16 + quad * 4 + r;
            if (q1i < 197) o[((size_t)b * NTOK + q1i) * 768 + dcol] = __float2bfloat16(o1[r]);
        }
    }
}

// ---------------------------------------------------------------------------
extern "C" void kernel_launch(void* const* d_in, const int* in_sizes, int n_in,
                              void* d_out, int out_size, void* d_ws, size_t ws_size,
                              hipStream_t stream) {
    const float* x      = (const float*)d_in[0];
    const float* conv_w = (const float*)d_in[1];
    const float* conv_b = (const float*)d_in[2];
    const float* cls_t  = (const float*)d_in[3];
    const float* pos    = (const float*)d_in[4];
    const float* qkv_w  = (const float*)d_in[5];
    const float* qkv_b  = (const float*)d_in[6];
    const float* proj_w = (const float*)d_in[7];
    const float* proj_b = (const float*)d_in[8];
    const float* n1_s   = (const float*)d_in[9];
    const float* n1_b   = (const float*)d_in[10];
    const float* n2_s   = (const float*)d_in[11];
    const float* n2_b   = (const float*)d_in[12];
    const float* fc1_w  = (const float*)d_in[13];
    const float* fc1_b  = (const float*)d_in[14];
    const float* fc2_w  = (const float*)d_in[15];
    const float* fc2_b  = (const float*)d_in[16];
    const float* enc_s  = (const float*)d_in[17];
    const float* enc_b  = (const float*)d_in[18];
    const float* head_w = (const float*)d_in[19];
    const float* head_b = (const float*)d_in[20];

    char* p = (char*)d_ws;
    auto take = [&](size_t bytes) -> char* {
        char* r = p;
        p += (bytes + 255) & ~(size_t)255;
        return r;
    };
    bf16* wb_layer = (bf16*)take((size_t)R_TOT * 2);            // 14.2 MB, reused per layer
    bf16* wb_conv  = (bf16*)take((size_t)589824 * 2);
    bf16* wb_head  = (bf16*)take((size_t)NCLS * 768 * 2);
    float* h       = (float*)take((size_t)MTOK * 768 * 4);      // residual stream, fp32
    bf16* y        = (bf16*)take((size_t)MTOK * 768 * 2);       // LN output
    char* qkv_raw  = take((size_t)MTOK * 2304 * 2);
    bf16* qkvb     = (bf16*)qkv_raw;
    float* pe_out  = (float*)qkv_raw;                           // alias (pre-loop only)
    bf16* o        = (bf16*)take((size_t)MTOK * 768 * 2);
    char* mid_raw  = take((size_t)MTOK * 3072 * 2);             // 77.5 MB
    bf16* mid      = (bf16*)mid_raw;
    bf16* peA      = (bf16*)mid_raw;                            // alias (pre-loop only)
    // vT aliases the upper part of mid_raw: lifetimes disjoint within a layer
    // (vT: qkv-gemm -> attn; mid: fc1 -> fc2).
    bf16* vT       = (bf16*)(mid_raw + (size_t)40 * 1024 * 1024);  // 22.0 MB
    bf16* yh       = (bf16*)take((size_t)128 * 768 * 2);

    // ---- patch embed ----
    cvt_kernel<<<576, 256, 0, stream>>>(conv_w, wb_conv, 589824);
    cvt_kernel<<<750, 256, 0, stream>>>(head_w, wb_head, NCLS * 768);
    im2row_kernel<<<37632, 256, 0, stream>>>(x, peA);
    gemm_kernel<true, false, false><<<dim3(6, 98), 256, 0, stream>>>(
        peA, wb_conv, conv_b, pe_out, 12544, 768, 768);
    assemble_kernel<<<37824, 256, 0, stream>>>(pe_out, cls_t, pos, h);

    // ---- transformer blocks ----
    for (int l = 0; l < 12; ++l) {
        cvt_layer_kernel<<<R_TOT / 4 / 256, 256, 0, stream>>>(
            qkv_w + (size_t)l * R_QKV, proj_w + (size_t)l * R_PRJ,
            fc1_w + (size_t)l * R_FC, fc2_w + (size_t)l * R_FC, wb_layer);
        ln_kernel<<<MTOK, 256, 0, stream>>>(h, 768, n1_s + l * 768, n1_b + l * 768, y);
        gemm_kernel<false, false, false><<<dim3(18, 99), 256, 0, stream>>>(
            y, wb_layer, qkv_b + l * 2304, qkvb, MTOK, 2304, 768);
        trv_kernel<<<3072, 256, 0, stream>>>(qkvb, vT);
        attn_kernel<<<768, 256, 0, stream>>>(qkvb, vT, o);
        gemm_kernel<true, true, false><<<dim3(6, 99), 256, 0, stream>>>(
            o, wb_layer + R_QKV, proj_b + l * 768, h, MTOK, 768, 768);
        ln_kernel<<<MTOK, 256, 0, stream>>>(h, 768, n2_s + l * 768, n2_b + l * 768, y);
        gemm_kernel<false, false, true><<<dim3(24, 99), 256, 0, stream>>>(
            y, wb_layer + R_QKV + R_PRJ, fc1_b + l * 3072, mid, MTOK, 3072, 768);
        gemm_kernel<true, true, false><<<dim3(6, 99), 256, 0, stream>>>(
            mid, wb_layer + R_QKV + R_PRJ + R_FC, fc2_b + l * 768, h, MTOK, 768, 3072);
    }

    // ---- head: LN over cls tokens, then [64,768] x [1000,768]^T ----
    ln_kernel<<<64, 256, 0, stream>>>(h, NTOK * 768, enc_s, enc_b, yh);
    gemm_kernel<true, false, false><<<dim3(8, 1), 256, 0, stream>>>(
        yh, wb_head, head_b, (float*)d_out, 64, NCLS, 768);
}

// Round 4
// 5933.641 us; speedup vs baseline: 1.3572x; 1.0209x over previous
//
#include <hip/hip_runtime.h>
#include <hip/hip_bf16.h>

typedef __hip_bfloat16 bf16;
typedef __attribute__((ext_vector_type(8))) short bf16x8;
typedef __attribute__((ext_vector_type(4))) float f32x4;

#define B_SZ 64
#define D_MODEL 768
#define NTOK 197
#define MTOK (B_SZ * NTOK)      // 12608
#define NHEAD 12
#define HDIM 64
#define MLP_DIM 3072
#define NCLS 1000

// direct HBM -> LDS DMA, 16B per lane. LDS dest = base + lane*16 (HW-fixed).
__device__ __forceinline__ void g2l16(const bf16* g, bf16* l) {
    __builtin_amdgcn_global_load_lds(
        (const __attribute__((address_space(1))) void*)g,
        (__attribute__((address_space(3))) void*)l, 16, 0, 0);
}

// Fast erf-based GELU (Abramowitz-Stegun 7.1.26, |err|<=1.5e-7 on erf —
// below bf16 output resolution). libm erff was ~2x the VALU cost.
__device__ __forceinline__ float gelu_f(float v) {
    float a = fabsf(v) * 0.70710678118654752f;
    float t = __builtin_amdgcn_rcpf(1.f + 0.3275911f * a);
    float p = t * (0.254829592f + t * (-0.284496736f + t * (1.421413741f +
              t * (-1.453152027f + t * 1.061405429f))));
    float er = 1.f - p * __expf(-a * a);
    er = v < 0.f ? -er : er;
    return 0.5f * v * (1.f + er);
}

// ---------------------------------------------------------------------------
// fp32 -> bf16 conversion (generic)
__global__ __launch_bounds__(256) void cvt_kernel(const float* __restrict__ in,
                                                  bf16* __restrict__ out, int n) {
    int i = ((int)blockIdx.x * 256 + (int)threadIdx.x) * 4;
    if (i >= n) return;
    float4 v = *(const float4*)(in + i);
    __align__(8) bf16 t[4] = {__float2bfloat16(v.x), __float2bfloat16(v.y),
                              __float2bfloat16(v.z), __float2bfloat16(v.w)};
    *(uint2*)(out + i) = *(uint2*)t;
}

// per-layer weight pack: qkv_w | proj_w | fc1_w | fc2_w  -> one bf16 buffer
#define R_QKV 1769472   // 2304*768
#define R_PRJ 589824    // 768*768
#define R_FC  2359296   // 3072*768
#define R_TOT 7077888
__global__ __launch_bounds__(256) void cvt_layer_kernel(
    const float* __restrict__ qw, const float* __restrict__ pw,
    const float* __restrict__ f1, const float* __restrict__ f2,
    bf16* __restrict__ out) {
    size_t i = ((size_t)blockIdx.x * 256 + threadIdx.x) * 4;   // < R_TOT
    const float* src;
    if (i < R_QKV)                src = qw + i;
    else if (i < R_QKV + R_PRJ)   src = pw + (i - R_QKV);
    else if (i < R_QKV + R_PRJ + R_FC) src = f1 + (i - R_QKV - R_PRJ);
    else                          src = f2 + (i - R_QKV - R_PRJ - R_FC);
    float4 v = *(const float4*)src;
    __align__(8) bf16 t[4] = {__float2bfloat16(v.x), __float2bfloat16(v.y),
                              __float2bfloat16(v.z), __float2bfloat16(v.w)};
    *(uint2*)(out + i) = *(uint2*)t;
}

// ---------------------------------------------------------------------------
// im2row for the patch-embed GEMM: x[B,3,224,224] -> A[12544][768] bf16
__global__ __launch_bounds__(256) void im2row_kernel(const float* __restrict__ x,
                                                     bf16* __restrict__ out) {
    size_t idx = (size_t)blockIdx.x * 256 + threadIdx.x;  // 12544*768 total
    int c = (int)(idx % 768);
    int r = (int)(idx / 768);
    int b = r / 196, pp = r % 196;
    int ph = pp / 14, pw = pp % 14;
    int ch = c >> 8, rem = c & 255;
    int i = rem >> 4, j = rem & 15;
    float v = x[(((size_t)b * 3 + ch) * 224 + ph * 16 + i) * 224 + pw * 16 + j];
    out[idx] = __float2bfloat16(v);
}

// assemble h[B,197,768] = concat(cls, patches) + pos
__global__ __launch_bounds__(256) void assemble_kernel(
    const float* __restrict__ pe, const float* __restrict__ cls,
    const float* __restrict__ pos, float* __restrict__ h) {
    size_t idx = (size_t)blockIdx.x * 256 + threadIdx.x;  // 64*197*768 total
    int d = (int)(idx % 768);
    size_t t_ = idx / 768;
    int t = (int)(t_ % 197);
    size_t b = t_ / 197;
    float v = (t == 0) ? cls[d] : pe[((size_t)b * 196 + (t - 1)) * 768 + d];
    h[idx] = v + pos[(size_t)t * 768 + d];
}

// ---------------------------------------------------------------------------
// LayerNorm over 768, one block per row. out is bf16 (GEMM A operand).
__global__ __launch_bounds__(256) void ln_kernel(
    const float* __restrict__ in, int row_stride,
    const float* __restrict__ sc, const float* __restrict__ bi,
    bf16* __restrict__ out) {
    const int row = blockIdx.x;
    const float* xr = in + (size_t)row * row_stride;
    const int tid = threadIdx.x;
    float v0 = xr[tid], v1 = xr[tid + 256], v2 = xr[tid + 512];
    float s = v0 + v1 + v2;
    float q = v0 * v0 + v1 * v1 + v2 * v2;
#pragma unroll
    for (int off = 32; off > 0; off >>= 1) {
        s += __shfl_down(s, off);
        q += __shfl_down(q, off);
    }
    __shared__ float sw[4], qw_[4];
    __shared__ float stat[2];
    int wv = tid >> 6;
    if ((tid & 63) == 0) { sw[wv] = s; qw_[wv] = q; }
    __syncthreads();
    if (tid == 0) {
        float S = sw[0] + sw[1] + sw[2] + sw[3];
        float Q = qw_[0] + qw_[1] + qw_[2] + qw_[3];
        float mean = S * (1.f / 768.f);
        float var = Q * (1.f / 768.f) - mean * mean;
        stat[0] = mean;
        stat[1] = rsqrtf(var + 1e-5f);
    }
    __syncthreads();
    float mean = stat[0], rstd = stat[1];
    size_t o0 = (size_t)row * 768;
    out[o0 + tid]       = __float2bfloat16((v0 - mean) * rstd * sc[tid]       + bi[tid]);
    out[o0 + tid + 256] = __float2bfloat16((v1 - mean) * rstd * sc[tid + 256] + bi[tid + 256]);
    out[o0 + tid + 512] = __float2bfloat16((v2 - mean) * rstd * sc[tid + 512] + bi[tid + 512]);
}

// ---------------------------------------------------------------------------
// Generic bf16 MFMA GEMM (m97-class: global_load_lds staging, XOR swizzle).
template <bool OUT_F32, bool RESID, bool GELU>
__global__ __launch_bounds__(256) void gemm_kernel(
    const bf16* __restrict__ A, const bf16* __restrict__ W,
    const float* __restrict__ bias, void* __restrict__ Cout,
    int M, int Nt, int K) {
    __shared__ __align__(16) bf16 As[128 * 64];
    __shared__ __align__(16) bf16 Bs[128 * 64];
    const int tid = threadIdx.x;
    const int lane = tid & 63;
    const int wave = tid >> 6;
    const int wm = wave >> 1, wn = wave & 1;
    const int m0 = blockIdx.y * 128, n0 = blockIdx.x * 128;
    const int m16 = lane & 15, kg = lane >> 4;

    f32x4 acc[4][4] = {};

    const int lr = lane >> 3;
    const int lc = ((lane & 7) ^ lr) * 8;          // swizzled chunk in row
    const bf16* aptr[4];
    const bf16* bptr[4];
    bf16* alds[4];
    bf16* blds[4];
#pragma unroll
    for (int c = 0; c < 4; ++c) {
        int rsub = wave * 32 + c * 8;
        int ra = m0 + rsub + lr; ra = ra < M ? ra : M - 1;    // clamp: no OOB
        int rb = n0 + rsub + lr; rb = rb < Nt ? rb : Nt - 1;
        aptr[c] = A + (size_t)ra * K + lc;
        bptr[c] = W + (size_t)rb * K + lc;
        alds[c] = &As[rsub * 64];
        blds[c] = &Bs[rsub * 64];
    }

    for (int k0 = 0; k0 < K; k0 += 64) {
        __syncthreads();
#pragma unroll
        for (int c = 0; c < 4; ++c) g2l16(aptr[c] + k0, alds[c]);
#pragma unroll
        for (int c = 0; c < 4; ++c) g2l16(bptr[c] + k0, blds[c]);
        __syncthreads();
#pragma unroll
        for (int ks = 0; ks < 2; ++ks) {
            bf16x8 af[4], bfv[4];
            const int ch = ((ks << 2) + kg) ^ (m16 & 7);
#pragma unroll
            for (int t = 0; t < 4; ++t)
                af[t] = *(const bf16x8*)&As[(wm * 64 + t * 16 + m16) * 64 + (ch << 3)];
#pragma unroll
            for (int t = 0; t < 4; ++t)
                bfv[t] = *(const bf16x8*)&Bs[(wn * 64 + t * 16 + m16) * 64 + (ch << 3)];
#pragma unroll
            for (int i = 0; i < 4; ++i)
#pragma unroll
                for (int j = 0; j < 4; ++j)
                    acc[i][j] = __builtin_amdgcn_mfma_f32_16x16x32_bf16(
                        af[i], bfv[j], acc[i][j], 0, 0, 0);
        }
    }
    const int quad = lane >> 4;
#pragma unroll
    for (int i = 0; i < 4; ++i) {
        const int rbase = m0 + wm * 64 + i * 16 + quad * 4;
#pragma unroll
        for (int j = 0; j < 4; ++j) {
            const int col = n0 + wn * 64 + j * 16 + m16;
            if (col >= Nt) continue;
            const float bv = bias[col];
#pragma unroll
            for (int r = 0; r < 4; ++r) {
                const int row = rbase + r;
                if (row >= M) continue;
                float v = acc[i][j][r] + bv;
                if (GELU) v = gelu_f(v);
                if (OUT_F32) {
                    float* op = (float*)Cout + (size_t)row * Nt + col;
                    if (RESID) *op += v; else *op = v;
                } else {
                    ((bf16*)Cout)[(size_t)row * Nt + col] = __float2bfloat16(v);
                }
            }
        }
    }
}

// ---------------------------------------------------------------------------
// V transpose: qkvb V-part -> vT[bh][64][256] (j in [197,256) zero).
// Stride 256 (NOT 224): the j0=192 block legitimately writes chunks up to
// j=255; with stride 224 those overflowed into the next d-row's j<32 and
// RACED with the j0=0 block (nondeterministic V corruption — fixed R4).
__global__ __launch_bounds__(256) void trv_kernel(const bf16* __restrict__ qkv,
                                                  bf16* __restrict__ vT) {
    __shared__ __align__(16) bf16 T[64 * 72];
    const int tid = threadIdx.x;
    const int bh = blockIdx.x >> 2;
    const int j0 = (blockIdx.x & 3) * 64;
    const int b = bh / NHEAD, hh = bh % NHEAD;
    const size_t vbase = (size_t)b * NTOK * 2304 + 1536 + (size_t)hh * 64;
    {
        int j = tid >> 2;
        int jj = j0 + j;
        int cpair = (tid & 3) * 2;
#pragma unroll
        for (int cc = 0; cc < 2; ++cc) {
            int c = cpair + cc;
            int4 v = make_int4(0, 0, 0, 0);
            if (jj < 197) v = *(const int4*)(qkv + vbase + (size_t)jj * 2304 + c * 8);
            *(int4*)&T[j * 72 + c * 8] = v;
        }
    }
    __syncthreads();
    {
        int d = tid >> 2;
#pragma unroll
        for (int cc = 0; cc < 2; ++cc) {
            int lch = (tid & 3) + cc * 4;     // local 16B chunk (8 j's)
            __align__(16) bf16 tmp[8];
#pragma unroll
            for (int u = 0; u < 8; ++u) tmp[u] = T[(lch * 8 + u) * 72 + d];
            *(int4*)(vT + ((size_t)bh * 64 + d) * 256 + j0 + lch * 8) = *(int4*)tmp;
        }
    }
}

// ---------------------------------------------------------------------------
// Fused attention (round-4): DMA Q staging, 3 barriers per q-tile (psum and
// Ps share one), 1/l deferred to the O epilogue. 80,896 B LDS -> 2 blocks/CU.
__global__ __launch_bounds__(256) void attn_kernel(const bf16* __restrict__ qkv,
                                                   const bf16* __restrict__ vT,
                                                   bf16* __restrict__ o) {
    __shared__ __align__(16) bf16 Ks[208 * 64];   // swizzled rows of 64
    __shared__ __align__(16) bf16 Vt[64 * 256];   // V^T rows (d), swizzled
    __shared__ __align__(16) bf16 Qs[32 * 64];    // swizzled
    __shared__ __align__(16) bf16 Ps[32 * 256];   // P (unnormalized e), A-layout
    __shared__ float pmax[4][32];
    __shared__ float psum[4][32];

    const int tid = threadIdx.x, lane = tid & 63, wave = tid >> 6;
    const int bh = blockIdx.x;
    const int b = bh / NHEAD, hh = bh % NHEAD;
    const size_t base = (size_t)b * NTOK * 2304 + hh * 64;
    const int m16 = lane & 15, kg = lane >> 4, quad = lane >> 4;

    // ---- one-time staging ----
    {
        const int lr = lane >> 3, lc7 = lane & 7;
        for (int g = wave; g < 25; g += 4) {
            int row = g * 8 + lr;
            if (row < 197)
                g2l16(qkv + base + 768 + (size_t)row * 2304 + ((lc7 ^ lr) * 8),
                      &Ks[g * 512]);
        }
        if (tid < 88) {   // zero K rows 197..207 (disjoint from DMA targets)
            int row = 197 + tid / 8, ch = tid % 8;
            *(int4*)&Ks[row * 64 + ch * 8] = make_int4(0, 0, 0, 0);
        }
        if (tid < 64) {   // zero Ps logical chunks 26..27 (cols 208..223)
            int row = tid >> 1, c = 26 + (tid & 1);
            *(int4*)&Ps[row * 256 + ((c ^ (row & 7)) * 8)] = make_int4(0, 0, 0, 0);
        }
        // V^T via DMA; vT stride is 256 so every logical chunk 0..31 exists
        // (j in [197,256) is deterministic zero from trv).
        const int vr = lane >> 5, vp = lane & 31;
        for (int g = wave; g < 32; g += 4) {
            int row = g * 2 + vr;
            g2l16(vT + ((size_t)bh * 64 + row) * 256 + ((vp ^ (row & 7)) * 8),
                  &Vt[g * 512]);
        }
    }
    __syncthreads();

    for (int qt = 0; qt < 7; ++qt) {
        {   // DMA-stage 32 Q rows; rows >= 197 keep stale data — garbage is
            // row-confined and those rows' stores are guarded.
            const int lr3 = lane >> 3;
            int row = wave * 8 + lr3;
            int qi = qt * 32 + row;
            if (qi < 197)
                g2l16(qkv + base + (size_t)qi * 2304 +
                          (((lane & 7) ^ (row & 7)) * 8),
                      &Qs[wave * 512]);
        }
        __syncthreads();

        bf16x8 qf[2][2];
#pragma unroll
        for (int mt = 0; mt < 2; ++mt)
#pragma unroll
            for (int ks = 0; ks < 2; ++ks)
                qf[mt][ks] = *(const bf16x8*)
                    &Qs[(mt * 16 + m16) * 64 + (((ks * 4 + kg) ^ (m16 & 7)) * 8)];

        // S = Q K^T : wave w owns n-tiles w, w+4, w+8, w+12(<13)
        f32x4 sacc[2][4];
#pragma unroll
        for (int mt = 0; mt < 2; ++mt)
#pragma unroll
            for (int t = 0; t < 4; ++t) sacc[mt][t] = (f32x4){0.f, 0.f, 0.f, 0.f};
#pragma unroll
        for (int t = 0; t < 4; ++t) {
            int nt = wave + 4 * t;
            if (nt < 13) {
#pragma unroll
                for (int ks = 0; ks < 2; ++ks) {
                    bf16x8 kf = *(const bf16x8*)
                        &Ks[(nt * 16 + m16) * 64 + (((ks * 4 + kg) ^ (m16 & 7)) * 8)];
                    sacc[0][t] = __builtin_amdgcn_mfma_f32_16x16x32_bf16(
                        qf[0][ks], kf, sacc[0][t], 0, 0, 0);
                    sacc[1][t] = __builtin_amdgcn_mfma_f32_16x16x32_bf16(
                        qf[1][ks], kf, sacc[1][t], 0, 0, 0);
                }
            }
        }
        // ---- in-register softmax (C-layout: row = quad*4+r, col = nt*16+m16)
        float pm[2][4];
#pragma unroll
        for (int mt = 0; mt < 2; ++mt)
#pragma unroll
            for (int r = 0; r < 4; ++r) pm[mt][r] = -3.0e38f;
#pragma unroll
        for (int t = 0; t < 4; ++t) {
            int nt = wave + 4 * t;
            bool v = (nt * 16 + m16) < 197;
#pragma unroll
            for (int mt = 0; mt < 2; ++mt)
#pragma unroll
                for (int r = 0; r < 4; ++r) {
                    float x = sacc[mt][t][r] * 0.125f;
                    sacc[mt][t][r] = x;
                    if (v) pm[mt][r] = fmaxf(pm[mt][r], x);
                }
        }
#pragma unroll
        for (int off = 1; off < 16; off <<= 1)
#pragma unroll
            for (int mt = 0; mt < 2; ++mt)
#pragma unroll
                for (int r = 0; r < 4; ++r)
                    pm[mt][r] = fmaxf(pm[mt][r], __shfl_xor(pm[mt][r], off));
        if (m16 == 0) {
#pragma unroll
            for (int mt = 0; mt < 2; ++mt)
#pragma unroll
                for (int r = 0; r < 4; ++r)
                    pmax[wave][mt * 16 + quad * 4 + r] = pm[mt][r];
        }
        __syncthreads();
        float fm[2][4];
#pragma unroll
        for (int mt = 0; mt < 2; ++mt)
#pragma unroll
            for (int r = 0; r < 4; ++r) {
                int row = mt * 16 + quad * 4 + r;
                fm[mt][r] = fmaxf(fmaxf(pmax[0][row], pmax[1][row]),
                                  fmaxf(pmax[2][row], pmax[3][row]));
            }
        float ps[2][4] = {};
#pragma unroll
        for (int t = 0; t < 4; ++t) {
            int nt = wave + 4 * t;
            bool v = (nt * 16 + m16) < 197;
#pragma unroll
            for (int mt = 0; mt < 2; ++mt)
#pragma unroll
                for (int r = 0; r < 4; ++r) {
                    float e = v ? __expf(sacc[mt][t][r] - fm[mt][r]) : 0.f;
                    sacc[mt][t][r] = e;
                    ps[mt][r] += e;
                }
        }
#pragma unroll
        for (int off = 1; off < 16; off <<= 1)
#pragma unroll
            for (int mt = 0; mt < 2; ++mt)
#pragma unroll
                for (int r = 0; r < 4; ++r)
                    ps[mt][r] += __shfl_xor(ps[mt][r], off);
        if (m16 == 0) {
#pragma unroll
            for (int mt = 0; mt < 2; ++mt)
#pragma unroll
                for (int r = 0; r < 4; ++r)
                    psum[wave][mt * 16 + quad * 4 + r] = ps[mt][r];
        }
        // write UNNORMALIZED P (e in (0,1]); 1/l applied at the O store
#pragma unroll
        for (int t = 0; t < 4; ++t) {
            int nt = wave + 4 * t;
            int col = nt * 16 + m16;
            if (col < 208) {
#pragma unroll
                for (int mt = 0; mt < 2; ++mt)
#pragma unroll
                    for (int r = 0; r < 4; ++r) {
                        int row = mt * 16 + quad * 4 + r;
                        Ps[row * 256 + (((col >> 3) ^ (row & 7)) * 8) + (col & 7)] =
                            __float2bfloat16(sacc[mt][t][r]);
                    }
            }
        }
        __syncthreads();   // one barrier covers psum + Ps
        // O = P V : wave w owns d-tile w
        f32x4 o0 = {0.f, 0.f, 0.f, 0.f}, o1 = {0.f, 0.f, 0.f, 0.f};
        const int vrow = wave * 16 + m16;
#pragma unroll
        for (int ks = 0; ks < 7; ++ks) {
            bf16x8 vf = *(const bf16x8*)
                &Vt[vrow * 256 + (((ks * 4 + kg) ^ (vrow & 7)) * 8)];
            bf16x8 p0 = *(const bf16x8*)
                &Ps[m16 * 256 + (((ks * 4 + kg) ^ (m16 & 7)) * 8)];
            bf16x8 p1 = *(const bf16x8*)
                &Ps[(16 + m16) * 256 + (((ks * 4 + kg) ^ (m16 & 7)) * 8)];
            o0 = __builtin_amdgcn_mfma_f32_16x16x32_bf16(p0, vf, o0, 0, 0, 0);
            o1 = __builtin_amdgcn_mfma_f32_16x16x32_bf16(p1, vf, o1, 0, 0, 0);
        }
        const int dcol = hh * 64 + wave * 16 + m16;
#pragma unroll
        for (int r = 0; r < 4; ++r) {
            int r0 = quad * 4 + r, r1 = 16 + quad * 4 + r;
            float i0 = 1.f / (psum[0][r0] + psum[1][r0] + psum[2][r0] + psum[3][r0]);
            float i1 = 1.f / (psum[0][r1] + psum[1][r1] + psum[2][r1] + psum[3][r1]);
            int q0i = qt * 32 + r0;
            if (q0i < 197)
                o[((size_t)b * NTOK + q0i) * 768 + dcol] = __float2bfloat16(o0[r] * i0);
            int q1i = qt * 32 + r1;
            if (q1i < 197)
                o[((size_t)b * NTOK + q1i) * 768 + dcol] = __float2bfloat16(o1[r] * i1);
        }
    }
}

// ---------------------------------------------------------------------------
extern "C" void kernel_launch(void* const* d_in, const int* in_sizes, int n_in,
                              void* d_out, int out_size, void* d_ws, size_t ws_size,
                              hipStream_t stream) {
    const float* x      = (const float*)d_in[0];
    const float* conv_w = (const float*)d_in[1];
    const float* conv_b = (const float*)d_in[2];
    const float* cls_t  = (const float*)d_in[3];
    const float* pos    = (const float*)d_in[4];
    const float* qkv_w  = (const float*)d_in[5];
    const float* qkv_b  = (const float*)d_in[6];
    const float* proj_w = (const float*)d_in[7];
    const float* proj_b = (const float*)d_in[8];
    const float* n1_s   = (const float*)d_in[9];
    const float* n1_b   = (const float*)d_in[10];
    const float* n2_s   = (const float*)d_in[11];
    const float* n2_b   = (const float*)d_in[12];
    const float* fc1_w  = (const float*)d_in[13];
    const float* fc1_b  = (const float*)d_in[14];
    const float* fc2_w  = (const float*)d_in[15];
    const float* fc2_b  = (const float*)d_in[16];
    const float* enc_s  = (const float*)d_in[17];
    const float* enc_b  = (const float*)d_in[18];
    const float* head_w = (const float*)d_in[19];
    const float* head_b = (const float*)d_in[20];

    char* p = (char*)d_ws;
    auto take = [&](size_t bytes) -> char* {
        char* r = p;
        p += (bytes + 255) & ~(size_t)255;
        return r;
    };
    bf16* wb_layer = (bf16*)take((size_t)R_TOT * 2);            // 14.2 MB, reused per layer
    bf16* wb_conv  = (bf16*)take((size_t)589824 * 2);
    bf16* wb_head  = (bf16*)take((size_t)NCLS * 768 * 2);
    float* h       = (float*)take((size_t)MTOK * 768 * 4);      // residual stream, fp32
    bf16* y        = (bf16*)take((size_t)MTOK * 768 * 2);       // LN output
    char* qkv_raw  = take((size_t)MTOK * 2304 * 2);
    bf16* qkvb     = (bf16*)qkv_raw;
    float* pe_out  = (float*)qkv_raw;                           // alias (pre-loop only)
    bf16* o        = (bf16*)take((size_t)MTOK * 768 * 2);
    char* mid_raw  = take((size_t)MTOK * 3072 * 2);             // 77.5 MB
    bf16* mid      = (bf16*)mid_raw;
    bf16* peA      = (bf16*)mid_raw;                            // alias (pre-loop only)
    // vT (stride-256: 25.2 MB) aliases upper mid_raw: lifetimes disjoint
    // within a layer (vT: qkv-gemm -> attn; mid: fc1 -> fc2).
    bf16* vT       = (bf16*)(mid_raw + (size_t)40 * 1024 * 1024);
    bf16* yh       = (bf16*)take((size_t)128 * 768 * 2);

    // ---- patch embed ----
    cvt_kernel<<<576, 256, 0, stream>>>(conv_w, wb_conv, 589824);
    cvt_kernel<<<750, 256, 0, stream>>>(head_w, wb_head, NCLS * 768);
    im2row_kernel<<<37632, 256, 0, stream>>>(x, peA);
    gemm_kernel<true, false, false><<<dim3(6, 98), 256, 0, stream>>>(
        peA, wb_conv, conv_b, pe_out, 12544, 768, 768);
    assemble_kernel<<<37824, 256, 0, stream>>>(pe_out, cls_t, pos, h);

    // ---- transformer blocks ----
    for (int l = 0; l < 12; ++l) {
        cvt_layer_kernel<<<R_TOT / 4 / 256, 256, 0, stream>>>(
            qkv_w + (size_t)l * R_QKV, proj_w + (size_t)l * R_PRJ,
            fc1_w + (size_t)l * R_FC, fc2_w + (size_t)l * R_FC, wb_layer);
        ln_kernel<<<MTOK, 256, 0, stream>>>(h, 768, n1_s + l * 768, n1_b + l * 768, y);
        gemm_kernel<false, false, false><<<dim3(18, 99), 256, 0, stream>>>(
            y, wb_layer, qkv_b + l * 2304, qkvb, MTOK, 2304, 768);
        trv_kernel<<<3072, 256, 0, stream>>>(qkvb, vT);
        attn_kernel<<<768, 256, 0, stream>>>(qkvb, vT, o);
        gemm_kernel<true, true, false><<<dim3(6, 99), 256, 0, stream>>>(
            o, wb_layer + R_QKV, proj_b + l * 768, h, MTOK, 768, 768);
        ln_kernel<<<MTOK, 256, 0, stream>>>(h, 768, n2_s + l * 768, n2_b + l * 768, y);
        gemm_kernel<false, false, true><<<dim3(24, 99), 256, 0, stream>>>(
            y, wb_layer + R_QKV + R_PRJ, fc1_b + l * 3072, mid, MTOK, 3072, 768);
        gemm_kernel<true, true, false><<<dim3(6, 99), 256, 0, stream>>>(
            mid, wb_layer + R_QKV + R_PRJ + R_FC, fc2_b + l * 768, h, MTOK, 768, 3072);
    }

    // ---- head: LN over cls tokens, then [64,768] x [1000,768]^T ----
    ln_kernel<<<64, 256, 0, stream>>>(h, NTOK * 768, enc_s, enc_b, yh);
    gemm_kernel<true, false, false><<<dim3(8, 1), 256, 0, stream>>>(
        yh, wb_head, head_b, (float*)d_out, 64, NCLS, 768);
}